// Round 1
// baseline (161.616 us; speedup 1.0000x reference)
//
#include <hip/hip_runtime.h>

// MultiHeadAttention (SAGAN-style reshape), B=C=1, T=3072, D=1024, H=16.
// Pipeline: cvt(fp32->fp16) -> fused QKV GEMM (fp16 MFMA) -> per-head repack
//        -> flash attention (swapped QK^T, online softmax, swizzled LDS)
//        -> transpose epilogue (gamma*out + residual).
// Workspace footprint: 48 MB (o_t reuses xb/wb region, dead after GEMM).

typedef _Float16 v8h __attribute__((ext_vector_type(8)));
typedef _Float16 v4h __attribute__((ext_vector_type(4)));
typedef float    v4f __attribute__((ext_vector_type(4)));

#define TSEQ 3072
#define DM   1024
#define NH   16
#define XD   64

__device__ __forceinline__ void async_load16(const void* g, void* l) {
  __builtin_amdgcn_global_load_lds(
      (const __attribute__((address_space(1))) unsigned int*)g,
      (__attribute__((address_space(3))) unsigned int*)l,
      16, 0, 0);
}

// ---------------- kernel 0: fp32 -> fp16 conversion -------------------------
extern "C" __global__ __launch_bounds__(256) void cvt_kernel(
    const float* __restrict__ x, const float* __restrict__ wq,
    const float* __restrict__ wk, const float* __restrict__ wv,
    _Float16* __restrict__ xb, _Float16* __restrict__ wb)
{
  const int NX4 = (TSEQ * DM) / 4;      // 786432 float4s in x
  const int NT  = NX4 * 2;              // + same count for concat(Wq,Wk,Wv)
  for (int i = blockIdx.x * blockDim.x + threadIdx.x; i < NT;
       i += gridDim.x * blockDim.x) {
    float4 v;
    _Float16* dst;
    if (i < NX4) {
      v = ((const float4*)x)[i];
      dst = xb + (size_t)i * 4;
    } else {
      const int j = i - NX4;            // float4 idx into wb; row n = j>>8
      const int n = j >> 8;
      if (n < 1024)      v = ((const float4*)wq)[j];
      else if (n < 2048) v = ((const float4*)wk)[j - 262144];
      else               v = ((const float4*)wv)[j - 524288];
      dst = wb + (size_t)j * 4;
    }
    v4h h;
    h[0] = (_Float16)v.x; h[1] = (_Float16)v.y;
    h[2] = (_Float16)v.z; h[3] = (_Float16)v.w;
    *(v4h*)dst = h;
  }
}

// ---------------- kernel 1: fused QKV GEMM ----------------------------------
// C[M=3072, N=3072] = xb[3072,1024] * wb[3072,1024]^T   (wb rows = output feats)
// m97 structure: 128x128 tile, 4 waves (2x2), BK=32, global_load_lds w=16.
extern "C" __global__ __launch_bounds__(256) void qkv_gemm_kernel(
    const _Float16* __restrict__ xb, const _Float16* __restrict__ wb,
    const float* __restrict__ bq, const float* __restrict__ bk,
    const float* __restrict__ bv,
    _Float16* __restrict__ qlin, _Float16* __restrict__ klin,
    _Float16* __restrict__ vlin)
{
  __shared__ _Float16 As[128 * 32];
  __shared__ _Float16 Bs[128 * 32];
  const int tid = threadIdx.x;
  const int w = tid >> 6, l = tid & 63;
  const int li = l & 15, lg = l >> 4;
  const int wm = w >> 1, wn = w & 1;
  const int m0 = blockIdx.y * 128, n0 = blockIdx.x * 128;
  v4f acc[4][4] = {};
  const int srow = l >> 2;        // 0..15: row within 16-row staging chunk
  const int scol = (l & 3) * 8;   // halves: 16B slot within 64B row
  for (int k0 = 0; k0 < DM; k0 += 32) {
#pragma unroll
    for (int c = 0; c < 2; ++c) {
      const int rbase = c * 64 + w * 16;
      async_load16(xb + (size_t)(m0 + rbase + srow) * DM + k0 + scol, &As[rbase * 32]);
      async_load16(wb + (size_t)(n0 + rbase + srow) * DM + k0 + scol, &Bs[rbase * 32]);
    }
    __syncthreads();
    v8h af[4], bf[4];
#pragma unroll
    for (int mi = 0; mi < 4; ++mi)
      af[mi] = *(const v8h*)&As[(wm * 64 + mi * 16 + li) * 32 + lg * 8];
#pragma unroll
    for (int ni = 0; ni < 4; ++ni)
      bf[ni] = *(const v8h*)&Bs[(wn * 64 + ni * 16 + li) * 32 + lg * 8];
#pragma unroll
    for (int mi = 0; mi < 4; ++mi)
#pragma unroll
      for (int ni = 0; ni < 4; ++ni)
        acc[mi][ni] = __builtin_amdgcn_mfma_f32_16x16x32_f16(
            af[mi], bf[ni], acc[mi][ni], 0, 0, 0);
    __syncthreads();
  }
  // epilogue: bias + fp16 store into the right projection
  const int which = n0 >> 10;          // 0=q 1=k 2=v (BN=128 divides 1024)
  const int ebase = n0 & 1023;
  const float* bias = which == 0 ? bq : (which == 1 ? bk : bv);
  _Float16* outp = which == 0 ? qlin : (which == 1 ? klin : vlin);
#pragma unroll
  for (int mi = 0; mi < 4; ++mi)
#pragma unroll
    for (int r = 0; r < 4; ++r) {
      const int t = m0 + wm * 64 + mi * 16 + lg * 4 + r;
#pragma unroll
      for (int ni = 0; ni < 4; ++ni) {
        const int e = ebase + wn * 64 + ni * 16 + li;
        outp[(size_t)t * DM + e] = (_Float16)(acc[mi][ni][r] + bias[e]);
      }
    }
}

// ---------------- kernel 2: per-head repack ---------------------------------
// qh/kh[h][i][x] = lin[t=x*48+i/64][e=(i%64)*16+h] ; vt[h][x][j] likewise.
extern "C" __global__ __launch_bounds__(256) void repack_kernel(
    const _Float16* __restrict__ qlin, const _Float16* __restrict__ klin,
    const _Float16* __restrict__ vlin,
    _Float16* __restrict__ qh, _Float16* __restrict__ kh,
    _Float16* __restrict__ vt)
{
  const int NE = NH * TSEQ * XD;   // 3145728
  for (int g = blockIdx.x * blockDim.x + threadIdx.x; g < 3 * NE;
       g += gridDim.x * blockDim.x) {
    if (g < 2 * NE) {
      const int gg = (g < NE) ? g : g - NE;
      const int xx = gg & 63;
      const int rest = gg >> 6;          // h*3072 + i
      const int h = rest / TSEQ;
      const int i = rest - h * TSEQ;
      const int t = xx * 48 + (i >> 6);
      const int e = ((i & 63) << 4) + h;
      if (g < NE) qh[gg] = qlin[t * DM + e];
      else        kh[gg] = klin[t * DM + e];
    } else {
      const int o = g - 2 * NE;
      const int j = o % TSEQ;
      const int rest = o / TSEQ;          // h*64 + x
      const int xx = rest & 63;
      const int h = rest >> 6;
      const int t = xx * 48 + (j >> 6);
      const int e = ((j & 63) << 4) + h;
      vt[o] = vlin[t * DM + e];
    }
  }
}

// ---------------- kernel 3: flash attention ---------------------------------
// 4 waves x 16 Q-rows, KVBLK=64. Swapped QK^T: mfma(A=K, B=Q) -> E^T with
// q-row i = lane&15 (lane-local softmax rows; reduce = shfl_xor 16,32).
// K/V/P tiles XOR-swizzled at 16B granularity (128B rows -> 16-way conflict
// otherwise). K/V staged via global_load_lds (linear dest, pre-swizzled src).
extern "C" __global__ __launch_bounds__(256) void attn_kernel(
    const _Float16* __restrict__ qh, const _Float16* __restrict__ kh,
    const _Float16* __restrict__ vt, float* __restrict__ o_t)
{
  __shared__ _Float16 Ks[64 * 64];       // [j][x], swizzled
  __shared__ _Float16 Vs[64 * 64];       // [x][j], swizzled
  __shared__ _Float16 Ps[4][16 * 64];    // per-wave [i][j], swizzled
  const int tid = threadIdx.x;
  const int w = tid >> 6, l = tid & 63;
  const int li = l & 15, lg = l >> 4;
  const int head = blockIdx.y;
  const int i0 = blockIdx.x * 64;
  const size_t hbase = (size_t)head * TSEQ * XD;

  v8h qf[2];
  {
    const _Float16* qrow = qh + hbase + (size_t)(i0 + w * 16 + li) * XD;
    qf[0] = *(const v8h*)(qrow + lg * 8);
    qf[1] = *(const v8h*)(qrow + 32 + lg * 8);
  }
  float mrun = -3.0e38f, lrun = 0.0f;
  v4f oacc[4] = {};

  for (int j0 = 0; j0 < TSEQ; j0 += 64) {
#pragma unroll
    for (int c = 0; c < 2; ++c) {
      const int rbase = c * 32 + w * 8;
      const int srow = rbase + (l >> 3);
      const int ss = ((l & 7) ^ (srow & 7)) * 8;   // pre-swizzled source slot
      async_load16(kh + hbase + (size_t)(j0 + srow) * XD + ss, &Ks[rbase * 64]);
      async_load16(vt + hbase + (size_t)srow * TSEQ + j0 + ss, &Vs[rbase * 64]);
    }
    __syncthreads();
    // QK^T (swapped): e4[kt] = E^T[j = kt*16+lg*4+r][i = li]
    v4f e4[4];
#pragma unroll
    for (int kt = 0; kt < 4; ++kt) {
      v4f a = {};
#pragma unroll
      for (int xk = 0; xk < 2; ++xk) {
        v8h kf = *(const v8h*)&Ks[(kt * 16 + li) * 64 +
                                  ((xk * 4 + lg) ^ (li & 7)) * 8];
        a = __builtin_amdgcn_mfma_f32_16x16x32_f16(kf, qf[xk], a, 0, 0, 0);
      }
      e4[kt] = a;
    }
    // online softmax over j (regs + lg-groups)
    float tm = -3.0e38f;
#pragma unroll
    for (int kt = 0; kt < 4; ++kt)
#pragma unroll
      for (int r = 0; r < 4; ++r) tm = fmaxf(tm, e4[kt][r]);
    tm = fmaxf(tm, __shfl_xor(tm, 16, 64));
    tm = fmaxf(tm, __shfl_xor(tm, 32, 64));
    const float mnew = fmaxf(mrun, tm);
    const float fsc = __expf(mrun - mnew);
    float ts = 0.0f;
    v4h pv[4];
#pragma unroll
    for (int kt = 0; kt < 4; ++kt)
#pragma unroll
      for (int r = 0; r < 4; ++r) {
        const float p = __expf(e4[kt][r] - mnew);
        ts += p;
        pv[kt][r] = (_Float16)p;
      }
    ts += __shfl_xor(ts, 16, 64);
    ts += __shfl_xor(ts, 32, 64);
    lrun = lrun * fsc + ts;
    mrun = mnew;
#pragma unroll
    for (int mi = 0; mi < 4; ++mi) oacc[mi] *= fsc;
    // write P[i=li][j], swizzled (16B slot s -> s^(li&7))
#pragma unroll
    for (int kt = 0; kt < 4; ++kt) {
      const int ps = (kt * 2 + (lg >> 1)) ^ (li & 7);
      *(v4h*)&Ps[w][li * 64 + ps * 8 + (lg & 1) * 4] = pv[kt];
    }
    // P·V: oacc[mi] = out^T[x = mi*16+lg*4+r][i = li]
#pragma unroll
    for (int jc = 0; jc < 2; ++jc) {
      v8h pf = *(const v8h*)&Ps[w][li * 64 + ((jc * 4 + lg) ^ (li & 7)) * 8];
#pragma unroll
      for (int mi = 0; mi < 4; ++mi) {
        v8h vf = *(const v8h*)&Vs[(mi * 16 + li) * 64 +
                                  ((jc * 4 + lg) ^ (li & 7)) * 8];
        oacc[mi] = __builtin_amdgcn_mfma_f32_16x16x32_f16(vf, pf, oacc[mi], 0, 0, 0);
      }
    }
    __syncthreads();
  }
  const float inv = 1.0f / lrun;
#pragma unroll
  for (int mi = 0; mi < 4; ++mi)
#pragma unroll
    for (int r = 0; r < 4; ++r) {
      const int xx = mi * 16 + lg * 4 + r;
      o_t[(size_t)(head * XD + xx) * TSEQ + i0 + w * 16 + li] = oacc[mi][r] * inv;
    }
}

// ---------------- kernel 4: transpose epilogue ------------------------------
// OUT[t][d] = gamma * o_t[d%16][d/16][t] + x[t][d]; LDS tile [64 t][256 d].
extern "C" __global__ __launch_bounds__(256) void epilogue_kernel(
    const float* __restrict__ o_t, const float* __restrict__ xin,
    const float* __restrict__ gscal, float* __restrict__ outp)
{
  __shared__ __align__(16) float lds[64 * 260];
  const int tid = threadIdx.x;
  const int t0 = blockIdx.x * 64;
  const int d0 = blockIdx.y * 256;
  const int x0 = d0 >> 4;
#pragma unroll
  for (int pass = 0; pass < 16; ++pass) {
    const int p = pass * 16 + (tid >> 4);   // 0..255 == lds col (= d-d0)
    const int h = p & 15, xx = p >> 4;
    const int tf = (tid & 15) * 4;
    const float4 v = *(const float4*)(o_t + (size_t)(h * XD + x0 + xx) * TSEQ + t0 + tf);
    lds[(tf + 0) * 260 + p] = v.x;
    lds[(tf + 1) * 260 + p] = v.y;
    lds[(tf + 2) * 260 + p] = v.z;
    lds[(tf + 3) * 260 + p] = v.w;
  }
  __syncthreads();
  const float g = gscal[0];
  const int row = tid >> 2;
  const int cb = ((tid & 3) ^ (row & 3)) * 64;   // xor-stagger the col block
  const int t = t0 + row;
#pragma unroll
  for (int c4 = 0; c4 < 64; c4 += 4) {
    const int c = cb + c4;
    const float4 xi = *(const float4*)(xin + (size_t)t * DM + d0 + c);
    const float4 ov = *(const float4*)&lds[row * 260 + c];
    float4 res;
    res.x = g * ov.x + xi.x;
    res.y = g * ov.y + xi.y;
    res.z = g * ov.z + xi.z;
    res.w = g * ov.w + xi.w;
    *(float4*)(outp + (size_t)t * DM + d0 + c) = res;
  }
}

extern "C" void kernel_launch(void* const* d_in, const int* in_sizes, int n_in,
                              void* d_out, int out_size, void* d_ws, size_t ws_size,
                              hipStream_t stream)
{
  const float* x  = (const float*)d_in[0];
  const float* Wq = (const float*)d_in[1];
  const float* bq = (const float*)d_in[2];
  const float* Wk = (const float*)d_in[3];
  const float* bk = (const float*)d_in[4];
  const float* Wv = (const float*)d_in[5];
  const float* bv = (const float*)d_in[6];
  const float* gm = (const float*)d_in[7];
  float* outp = (float*)d_out;
  char* ws = (char*)d_ws;
  const size_t SZH = (size_t)TSEQ * DM * sizeof(_Float16);   // 6 MB
  _Float16* xb   = (_Float16*)(ws);                 // [0,6)   MB
  _Float16* wb   = (_Float16*)(ws + SZH);           // [6,12)  MB
  _Float16* qlin = (_Float16*)(ws + 2 * SZH);       // [12,18) MB
  _Float16* klin = (_Float16*)(ws + 3 * SZH);       // [18,24) MB
  _Float16* vlin = (_Float16*)(ws + 4 * SZH);       // [24,30) MB
  _Float16* qhp  = (_Float16*)(ws + 5 * SZH);       // [30,36) MB
  _Float16* khp  = (_Float16*)(ws + 6 * SZH);       // [36,42) MB
  _Float16* vtp  = (_Float16*)(ws + 7 * SZH);       // [42,48) MB
  float*    o_t  = (float*)(ws);                    // reuses [0,12) MB (xb/wb dead)

  cvt_kernel<<<dim3(2048), dim3(256), 0, stream>>>(x, Wq, Wk, Wv, xb, wb);
  qkv_gemm_kernel<<<dim3(24, 24), dim3(256), 0, stream>>>(xb, wb, bq, bk, bv,
                                                          qlin, klin, vlin);
  repack_kernel<<<dim3(4096), dim3(256), 0, stream>>>(qlin, klin, vlin,
                                                      qhp, khp, vtp);
  attn_kernel<<<dim3(48, 16), dim3(256), 0, stream>>>(qhp, khp, vtp, o_t);
  epilogue_kernel<<<dim3(48, 4), dim3(256), 0, stream>>>(o_t, x, gm, outp);
  (void)in_sizes; (void)n_in; (void)out_size; (void)ws_size;
}